// Round 1
// baseline (176.811 us; speedup 1.0000x reference)
//
#include <hip/hip_runtime.h>
#include <hip/hip_bf16.h>
#include <stdint.h>

#define NV   65536   // active voxels
#define KOFF 27      // kernel offsets
#define CIN  128
#define COUT 128

typedef __bf16 bf16x8 __attribute__((ext_vector_type(8)));
typedef float  f32x4  __attribute__((ext_vector_type(4)));

__device__ __forceinline__ void async_copy16(void* lds, const void* g) {
    __builtin_amdgcn_global_load_lds(
        (const __attribute__((address_space(1))) void*)g,
        (__attribute__((address_space(3))) void*)lds,
        16, 0, 0);
}

// ---- prep kernels -------------------------------------------------------

// features fp32 [N,128] -> bf16 [(N+1),128], row N = zeros
__global__ void k_prep_feat(const float* __restrict__ f,
                            __hip_bfloat16* __restrict__ fb,
                            int total, int nvalid) {
    int i = blockIdx.x * 256 + threadIdx.x;
    if (i < total) {
        float v = (i < nvalid) ? f[i] : 0.0f;
        fb[i] = __float2bfloat16(v);
    }
}

// weight fp32 [K][cin][cout] -> bf16 transposed [K][cout][cin]
__global__ void k_prep_w(const float* __restrict__ w,
                         __hip_bfloat16* __restrict__ wt) {
    int i = blockIdx.x * 256 + threadIdx.x;
    if (i < KOFF * CIN * COUT) {
        int k    = i >> 14;          // /16384
        int cin  = (i >> 7) & 127;
        int cout = i & 127;
        wt[k * 16384 + cout * 128 + cin] = __float2bfloat16(w[i]);
    }
}

// nbr[k][(N+1)] init to N (zero row)
__global__ void k_init_nbr(int* __restrict__ nbr, int total) {
    int i = blockIdx.x * 256 + threadIdx.x;
    if (i < total) nbr[i] = NV;
}

// scatter rulebook: nbr[k][out_row] = in_row  (padded pairs land in row N)
__global__ void k_scatter_nbr(const int* __restrict__ in_idx,
                              const int* __restrict__ out_idx,
                              int* __restrict__ nbr) {
    int i = blockIdx.x * 256 + threadIdx.x;
    if (i < KOFF * NV) {
        int k = i >> 16;        // / NV (power of two)
        int o = out_idx[i];     // in [0, NV]
        nbr[k * (NV + 1) + o] = in_idx[i];
    }
}

// ---- main gather-GEMM kernel -------------------------------------------
// block = 256 thr (4 waves 2x2), tile = 128 out-rows x 128 out-cols
// per offset k: stage gathered A (128x128 bf16) + Wt_k (128x128 bf16) in LDS,
// 4 k-steps of mfma 16x16x32 bf16. XOR-chunk swizzle for bank conflicts.
__global__ __launch_bounds__(256, 2)
void sp_conv_main(const __hip_bfloat16* __restrict__ feats,
                  const __hip_bfloat16* __restrict__ wt,
                  const int* __restrict__ nbr,
                  const float* __restrict__ bias,
                  float* __restrict__ out) {
    __shared__ unsigned char smem[65536];
    unsigned char* smA = smem;           // 32 KB
    unsigned char* smB = smem + 32768;   // 32 KB

    const int t   = threadIdx.x;
    const int bid = blockIdx.x;
    // XCD swizzle: consecutive 64-tile ranges per XCD for L2 gather locality
    const int tile0 = ((bid & 7) * 64 + (bid >> 3)) * 128;

    const int w    = t >> 6;
    const int lane = t & 63;
    const int lr   = lane & 15;
    const int quad = lane >> 4;
    const int m0   = (w >> 1) * 64;
    const int n0   = (w & 1) * 64;

    // staging-side mapping: LDS slot (row = i*16 + t/16, physchunk = t&15)
    // holds global 16B chunk c = (t&15) ^ (t/16)   [row&15 == t/16]
    const int srow   = t >> 4;
    const int sbyte  = ((t & 15) ^ srow) * 16;

    f32x4 acc[4][4] = {};  // zero-init

    const unsigned char* featsB = (const unsigned char*)feats;
    const unsigned char* wtB    = (const unsigned char*)wt;

    for (int k = 0; k < KOFF; ++k) {
        const int* nbrk = nbr + k * (NV + 1) + tile0;
        const unsigned char* wk = wtB + (size_t)k * 32768;
        #pragma unroll
        for (int i = 0; i < 8; ++i) {
            int r = i * 16 + srow;
            int arow = nbrk[r];
            async_copy16(smA + i * 4096 + t * 16,
                         featsB + (size_t)arow * 256 + sbyte);
            async_copy16(smB + i * 4096 + t * 16,
                         wk + r * 256 + sbyte);
        }
        __syncthreads();   // drains vmcnt (global_load_lds) + barrier

        #pragma unroll
        for (int ks = 0; ks < 4; ++ks) {
            bf16x8 af[4], bfr[4];
            #pragma unroll
            for (int mt = 0; mt < 4; ++mt) {
                int row = m0 + mt * 16 + lr;
                int pch = ((ks * 4 + quad) ^ lr) * 16;
                af[mt] = *(const bf16x8*)(smA + row * 256 + pch);
            }
            #pragma unroll
            for (int nt = 0; nt < 4; ++nt) {
                int row = n0 + nt * 16 + lr;
                int pch = ((ks * 4 + quad) ^ lr) * 16;
                bfr[nt] = *(const bf16x8*)(smB + row * 256 + pch);
            }
            #pragma unroll
            for (int mt = 0; mt < 4; ++mt)
                #pragma unroll
                for (int nt = 0; nt < 4; ++nt)
                    acc[mt][nt] = __builtin_amdgcn_mfma_f32_16x16x32_bf16(
                        af[mt], bfr[nt], acc[mt][nt], 0, 0, 0);
        }
        __syncthreads();
    }

    // epilogue: C/D layout col = lane&15, row = quad*4 + reg
    float bv[4];
    #pragma unroll
    for (int nt = 0; nt < 4; ++nt) bv[nt] = bias[n0 + nt * 16 + lr];

    #pragma unroll
    for (int mt = 0; mt < 4; ++mt) {
        #pragma unroll
        for (int nt = 0; nt < 4; ++nt) {
            #pragma unroll
            for (int r = 0; r < 4; ++r) {
                int grow = tile0 + m0 + mt * 16 + quad * 4 + r;
                out[(size_t)grow * COUT + n0 + nt * 16 + lr] =
                    acc[mt][nt][r] + bv[nt];
            }
        }
    }
}

// ---- launch -------------------------------------------------------------

extern "C" void kernel_launch(void* const* d_in, const int* in_sizes, int n_in,
                              void* d_out, int out_size, void* d_ws, size_t ws_size,
                              hipStream_t stream) {
    const float* features = (const float*)d_in[0];   // [N,128] f32
    const float* weight   = (const float*)d_in[1];   // [27,128,128] f32
    const float* bias     = (const float*)d_in[2];   // [128] f32
    const int*   in_idx   = (const int*)d_in[3];     // [27,N] i32
    const int*   out_idx  = (const int*)d_in[4];     // [27,N] i32
    float* out = (float*)d_out;                      // [N,128] f32

    uint8_t* ws = (uint8_t*)d_ws;
    size_t off = 0;
    __hip_bfloat16* feats_bf = (__hip_bfloat16*)(ws + off);       // (N+1)*128*2
    off += (size_t)(NV + 1) * CIN * 2;
    off = (off + 255) & ~(size_t)255;
    __hip_bfloat16* wt_bf = (__hip_bfloat16*)(ws + off);          // 27*128*128*2
    off += (size_t)KOFF * CIN * COUT * 2;
    off = (off + 255) & ~(size_t)255;
    int* nbr = (int*)(ws + off);                                  // 27*(N+1)*4

    {   // cast features -> bf16 (+ zero row N)
        int total = (NV + 1) * CIN;
        k_prep_feat<<<(total + 255) / 256, 256, 0, stream>>>(
            features, feats_bf, total, NV * CIN);
    }
    {   // transpose+cast weight
        int total = KOFF * CIN * COUT;
        k_prep_w<<<(total + 255) / 256, 256, 0, stream>>>(weight, wt_bf);
    }
    {   // init nbr to dummy row
        int total = KOFF * (NV + 1);
        k_init_nbr<<<(total + 255) / 256, 256, 0, stream>>>(nbr, total);
    }
    {   // scatter rulebook into nbr table
        int total = KOFF * NV;
        k_scatter_nbr<<<(total + 255) / 256, 256, 0, stream>>>(
            in_idx, out_idx, nbr);
    }
    // main gather-GEMM: 512 tiles of 128 rows
    sp_conv_main<<<NV / 128, 256, 0, stream>>>(feats_bf, wt_bf, nbr, bias, out);
}

// Round 2
// 168.985 us; speedup vs baseline: 1.0463x; 1.0463x over previous
//
#include <hip/hip_runtime.h>
#include <hip/hip_bf16.h>
#include <stdint.h>

#define NV   65536   // active voxels
#define KOFF 27      // kernel offsets
#define CIN  128
#define COUT 128

typedef __bf16 bf16x8 __attribute__((ext_vector_type(8)));
typedef float  f32x4  __attribute__((ext_vector_type(4)));

__device__ __forceinline__ void async_copy16(void* lds, const void* g) {
    __builtin_amdgcn_global_load_lds(
        (const __attribute__((address_space(1))) void*)g,
        (__attribute__((address_space(3))) void*)lds,
        16, 0, 0);
}

// ---- prep kernels -------------------------------------------------------

// features fp32 [N,128] -> bf16 [(N+1),128], row N = zeros.
// Vectorized x8: two float4 loads + one 16B store per thread.
__global__ void k_prep_feat(const float* __restrict__ f,
                            uint4* __restrict__ fb4,
                            int total8, int nvalid8) {
    int i = blockIdx.x * 256 + threadIdx.x;
    if (i >= total8) return;
    union { uint4 u; __hip_bfloat16 h[8]; } p;
    if (i < nvalid8) {
        const float4* f4 = (const float4*)f;
        float4 a = f4[i * 2];
        float4 b = f4[i * 2 + 1];
        p.h[0] = __float2bfloat16(a.x);
        p.h[1] = __float2bfloat16(a.y);
        p.h[2] = __float2bfloat16(a.z);
        p.h[3] = __float2bfloat16(a.w);
        p.h[4] = __float2bfloat16(b.x);
        p.h[5] = __float2bfloat16(b.y);
        p.h[6] = __float2bfloat16(b.z);
        p.h[7] = __float2bfloat16(b.w);
    } else {
        p.u = make_uint4(0, 0, 0, 0);   // zero row N
    }
    fb4[i] = p.u;
}

// weight fp32 [K][cin][cout] -> bf16 transposed [K][cout][cin]
// (small: 0.9 MB out; scatter 2B stores are acceptable)
__global__ void k_prep_w(const float* __restrict__ w,
                         __hip_bfloat16* __restrict__ wt) {
    int i = blockIdx.x * 256 + threadIdx.x;
    if (i < KOFF * CIN * COUT) {
        int k    = i >> 14;          // /16384
        int cin  = (i >> 7) & 127;
        int cout = i & 127;
        wt[k * 16384 + cout * 128 + cin] = __float2bfloat16(w[i]);
    }
}

// scatter rulebook: nbr[k][out_row] = in_row. nbr pre-memset to 0xFF (-1);
// main kernel clamps -1 -> zero row NV. Vectorized x4.
__global__ void k_scatter_nbr(const int4* __restrict__ in4,
                              const int4* __restrict__ out4,
                              int* __restrict__ nbr) {
    int i = blockIdx.x * 256 + threadIdx.x;
    if (i < KOFF * NV / 4) {
        int k = i >> 14;            // / (NV/4)
        int4 ii = in4[i];
        int4 oo = out4[i];
        int* nb = nbr + k * (NV + 1);
        nb[oo.x] = ii.x;
        nb[oo.y] = ii.y;
        nb[oo.z] = ii.z;
        nb[oo.w] = ii.w;
    }
}

// ---- main gather-GEMM kernel -------------------------------------------
// block = 256 thr (4 waves 2x2), tile = 128 out-rows x 128 out-cols
// per offset k: stage gathered A (128x128 bf16) + Wt_k (128x128 bf16) in LDS,
// 4 k-steps of mfma 16x16x32 bf16. XOR-chunk swizzle for bank conflicts.
// nbr indices for offset k+1 prefetched during compute of offset k.
__global__ __launch_bounds__(256, 2)
void sp_conv_main(const __hip_bfloat16* __restrict__ feats,
                  const __hip_bfloat16* __restrict__ wt,
                  const int* __restrict__ nbr,
                  const float* __restrict__ bias,
                  float* __restrict__ out) {
    __shared__ unsigned char smem[65536];
    unsigned char* smA = smem;           // 32 KB
    unsigned char* smB = smem + 32768;   // 32 KB

    const int t   = threadIdx.x;
    const int bid = blockIdx.x;
    // XCD swizzle: consecutive 64-tile ranges per XCD for L2 gather locality
    const int tile0 = ((bid & 7) * 64 + (bid >> 3)) * 128;

    const int w    = t >> 6;
    const int lane = t & 63;
    const int lr   = lane & 15;
    const int quad = lane >> 4;
    const int m0   = (w >> 1) * 64;
    const int n0   = (w & 1) * 64;

    // staging-side mapping: LDS slot (row = i*16 + t/16, physchunk = t&15)
    // holds global 16B chunk c = (t&15) ^ (row&15)   [row&15 == t/16]
    const int srow   = t >> 4;
    const int sbyte  = ((t & 15) ^ srow) * 16;

    f32x4 acc[4][4] = {};  // zero-init

    const unsigned char* featsB = (const unsigned char*)feats;
    const unsigned char* wtB    = (const unsigned char*)wt;

    // prefetch offset-0 neighbor rows
    int arows[8];
    {
        const int* nbr0 = nbr + tile0;
        #pragma unroll
        for (int i = 0; i < 8; ++i) arows[i] = nbr0[i * 16 + srow];
    }

    for (int k = 0; k < KOFF; ++k) {
        const unsigned char* wk = wtB + (size_t)k * 32768;
        #pragma unroll
        for (int i = 0; i < 8; ++i) {
            unsigned ar = min((unsigned)arows[i], (unsigned)NV);  // -1 -> zero row
            async_copy16(smA + i * 4096 + t * 16,
                         featsB + (size_t)ar * 256 + sbyte);
            async_copy16(smB + i * 4096 + t * 16,
                         wk + (i * 16 + srow) * 256 + sbyte);
        }
        __syncthreads();   // drains vmcnt (global_load_lds) + barrier

        // prefetch next offset's neighbor rows (latency hidden by MFMA phase)
        if (k + 1 < KOFF) {
            const int* nbrn = nbr + (k + 1) * (NV + 1) + tile0;
            #pragma unroll
            for (int i = 0; i < 8; ++i) arows[i] = nbrn[i * 16 + srow];
        }

        #pragma unroll
        for (int ks = 0; ks < 4; ++ks) {
            bf16x8 af[4], bfr[4];
            #pragma unroll
            for (int mt = 0; mt < 4; ++mt) {
                int row = m0 + mt * 16 + lr;
                int pch = ((ks * 4 + quad) ^ lr) * 16;
                af[mt] = *(const bf16x8*)(smA + row * 256 + pch);
            }
            #pragma unroll
            for (int nt = 0; nt < 4; ++nt) {
                int row = n0 + nt * 16 + lr;
                int pch = ((ks * 4 + quad) ^ lr) * 16;
                bfr[nt] = *(const bf16x8*)(smB + row * 256 + pch);
            }
            #pragma unroll
            for (int mt = 0; mt < 4; ++mt)
                #pragma unroll
                for (int nt = 0; nt < 4; ++nt)
                    acc[mt][nt] = __builtin_amdgcn_mfma_f32_16x16x32_bf16(
                        af[mt], bfr[nt], acc[mt][nt], 0, 0, 0);
        }
        __syncthreads();
    }

    // epilogue: C/D layout col = lane&15, row = quad*4 + reg
    float bv[4];
    #pragma unroll
    for (int nt = 0; nt < 4; ++nt) bv[nt] = bias[n0 + nt * 16 + lr];

    #pragma unroll
    for (int mt = 0; mt < 4; ++mt) {
        #pragma unroll
        for (int nt = 0; nt < 4; ++nt) {
            #pragma unroll
            for (int r = 0; r < 4; ++r) {
                int grow = tile0 + m0 + mt * 16 + quad * 4 + r;
                out[(size_t)grow * COUT + n0 + nt * 16 + lr] =
                    acc[mt][nt][r] + bv[nt];
            }
        }
    }
}

// ---- launch -------------------------------------------------------------

extern "C" void kernel_launch(void* const* d_in, const int* in_sizes, int n_in,
                              void* d_out, int out_size, void* d_ws, size_t ws_size,
                              hipStream_t stream) {
    const float* features = (const float*)d_in[0];   // [N,128] f32
    const float* weight   = (const float*)d_in[1];   // [27,128,128] f32
    const float* bias     = (const float*)d_in[2];   // [128] f32
    const int*   in_idx   = (const int*)d_in[3];     // [27,N] i32
    const int*   out_idx  = (const int*)d_in[4];     // [27,N] i32
    float* out = (float*)d_out;                      // [N,128] f32

    uint8_t* ws = (uint8_t*)d_ws;
    size_t off = 0;
    __hip_bfloat16* feats_bf = (__hip_bfloat16*)(ws + off);       // (N+1)*128*2
    off += (size_t)(NV + 1) * CIN * 2;
    off = (off + 255) & ~(size_t)255;
    __hip_bfloat16* wt_bf = (__hip_bfloat16*)(ws + off);          // 27*128*128*2
    off += (size_t)KOFF * CIN * COUT * 2;
    off = (off + 255) & ~(size_t)255;
    int* nbr = (int*)(ws + off);                                  // 27*(N+1)*4

    {   // cast features -> bf16 (+ zero row N), x8 vectorized
        int total8  = (NV + 1) * CIN / 8;   // 1048592
        int nvalid8 = NV * CIN / 8;
        k_prep_feat<<<(total8 + 255) / 256, 256, 0, stream>>>(
            features, (uint4*)feats_bf, total8, nvalid8);
    }
    {   // transpose+cast weight
        int total = KOFF * CIN * COUT;
        k_prep_w<<<(total + 255) / 256, 256, 0, stream>>>(weight, wt_bf);
    }
    // init nbr to 0xFFFFFFFF (-1 = "no neighbor"; main clamps to zero row)
    hipMemsetAsync(nbr, 0xFF, (size_t)KOFF * (NV + 1) * 4, stream);
    {   // scatter rulebook into nbr table, x4 vectorized
        int total4 = KOFF * NV / 4;
        k_scatter_nbr<<<(total4 + 255) / 256, 256, 0, stream>>>(
            (const int4*)in_idx, (const int4*)out_idx, nbr);
    }
    // main gather-GEMM: 512 tiles of 128 rows
    sp_conv_main<<<NV / 128, 256, 0, stream>>>(feats_bf, wt_bf, nbr, bias, out);
}